// Round 8
// baseline (71.180 us; speedup 1.0000x reference)
//
#include <hip/hip_runtime.h>
#include <math.h>

// Problem geometry
#define MTOT  16384      // B*L
#define DM    1024
#define HIDN  128
#define HNB   256
#define NBAT  4
#define CLK   64         // rows per k_mega block == scan chunk
#define NBLK  256        // MTOT/CLK
#define CPB   64         // chunks per batch (4096/64)

typedef _Float16 v8h __attribute__((ext_vector_type(8)));
typedef float    v4f __attribute__((ext_vector_type(4)));
#define MFMA16(a,b,c) __builtin_amdgcn_mfma_f32_16x16x32_f16((a),(b),(c),0,0,0)

// Weight blobs (in d_ws when big enough, else out1 region):
//  [0,655360):      W1 k-tiles kt=0..31, 20480 B: {W1h[col=128][40 fp16] | W1l}
//  [655360,819200): W2 k-tiles ks=0..3, 40960 B: {W2h[col=256][40] | W2l}
#define W1BLOB_TILE 20480
#define W2BLOB_BASE 655360
#define W2BLOB_TILE 40960
#define BLOB_BYTES  819200

// liveness keepers: stop hipcc sinking/rematerializing prefetch loads
#define KEEPF4(v) asm volatile("" : "+v"((v).x), "+v"((v).y), "+v"((v).z), "+v"((v).w))
#define KEEPI4(v) asm volatile("" : "+v"((v).x), "+v"((v).y), "+v"((v).z), "+v"((v).w))

// barrier draining LDS only — global prefetches stay in flight
#define BAR_LGKM() do { \
    asm volatile("s_waitcnt lgkmcnt(0)" ::: "memory"); \
    __builtin_amdgcn_s_barrier(); \
    __builtin_amdgcn_sched_barrier(0); \
} while (0)

union U16 { int4 i; v8h h; };

__device__ __forceinline__ void cvt_store(float4 v, char* ph, char* pl) {
    union { _Float16 h[4]; int2 i; } H, L;
    float a[4] = {v.x, v.y, v.z, v.w};
    #pragma unroll
    for (int e = 0; e < 4; ++e) {
        _Float16 hh = (_Float16)a[e];
        H.h[e] = hh;
        L.h[e] = (_Float16)((a[e] - (float)hh) * 4096.f);
    }
    *(int2*)ph = H.i;
    *(int2*)pl = L.i;
}

// ---------------------------------------------------------------------------
// K0: convert+transpose+pad weights into fp16 split blobs (unchanged R4-R7).
// ---------------------------------------------------------------------------
__global__ __launch_bounds__(256) void k_prep(
    const float* __restrict__ W1,   // [1024][128]
    const float* __restrict__ W2,   // [128][256]
    char* __restrict__ blobs)
{
    __shared__ float lds[32][260];
    const int t = threadIdx.x, blk = blockIdx.x;
    if (blk < 32) {
        const int k0 = blk * 32;
        #pragma unroll
        for (int i = 0; i < 4; ++i) {
            int j = t + i * 256;
            int k = j >> 5, n4 = (j & 31) << 2;
            *(float4*)&lds[k][n4] = *(const float4*)&W1[(size_t)(k0 + k) * HIDN + n4];
        }
        __syncthreads();
        const int n = t >> 1, kh = t & 1;
        union { _Float16 h[16]; int2 v[4]; } uh, ul;
        #pragma unroll
        for (int kk = 0; kk < 16; ++kk) {
            float v = lds[kh * 16 + kk][n];
            _Float16 hh = (_Float16)v;
            uh.h[kk] = hh;
            ul.h[kk] = (_Float16)((v - (float)hh) * 4096.f);
        }
        char* bh = blobs + blk * W1BLOB_TILE + n * 80 + kh * 32;
        #pragma unroll
        for (int i = 0; i < 4; ++i) {
            *(int2*)(bh + i * 8)         = uh.v[i];
            *(int2*)(bh + 10240 + i * 8) = ul.v[i];
        }
        if (kh == 1) {
            int2 z; z.x = 0; z.y = 0;
            char* ph = blobs + blk * W1BLOB_TILE + n * 80 + 64;
            *(int2*)(ph) = z; *(int2*)(ph + 8) = z;
            *(int2*)(ph + 10240) = z; *(int2*)(ph + 10240 + 8) = z;
        }
    } else {
        const int ks = blk - 32, k0 = ks * 32;
        #pragma unroll
        for (int i = 0; i < 8; ++i) {
            int j = t + i * 256;
            int k = j >> 6, n4 = (j & 63) << 2;
            *(float4*)&lds[k][n4] = *(const float4*)&W2[(size_t)(k0 + k) * HNB + n4];
        }
        __syncthreads();
        const int n = t;
        union { _Float16 h[40]; int2 v[10]; } uh, ul;
        #pragma unroll
        for (int kk = 0; kk < 32; ++kk) {
            float v = lds[kk][n];
            _Float16 hh = (_Float16)v;
            uh.h[kk] = hh;
            ul.h[kk] = (_Float16)((v - (float)hh) * 4096.f);
        }
        #pragma unroll
        for (int kk = 32; kk < 40; ++kk) { uh.h[kk] = (_Float16)0.f; ul.h[kk] = (_Float16)0.f; }
        char* bh = blobs + W2BLOB_BASE + ks * W2BLOB_TILE + n * 80;
        #pragma unroll
        for (int i = 0; i < 10; ++i) {
            *(int2*)(bh + i * 8)         = uh.v[i];
            *(int2*)(bh + 20480 + i * 8) = ul.v[i];
        }
    }
}

// ---------------------------------------------------------------------------
// K1: mega. Block = 64 rows = one chunk; 512 thr (8 waves = 4 gN x 2 gK),
// grid 256 (1 block/CU). Wave GEMM1 tile 64x32 (mP=4, nP=2), in-block K-split
// (gk halves), partial combine in LDS. A: HBM -> dist-4 reg ring -> swizzled
// LDS dbuf (4 tile slots). W: register-direct from L2 blob, dist-1 ring.
// Keepers pin all prefetch registers. Then GELU->H(LDS), GEMM2 (wave 64x32),
// z=pi*tanh -> LDS, in-block scan, S/K(/Pi/R) stores, chunk carry.
// ---------------------------------------------------------------------------
__global__ __launch_bounds__(512, 2) void k_mega(
    const float* __restrict__ A,      // content [16384][1024]
    const float* __restrict__ theta,  // [16384][256]
    const float* __restrict__ b1, const float* __restrict__ b2,
    const float* __restrict__ logPi, const float* __restrict__ logR,
    const char* __restrict__ blobs,
    float* __restrict__ out0, float* __restrict__ out2,
    float* fill1, float* fill3,       // non-null only in ws mode
    float* carry, int cstride)
{
    // LDS map (67584 B):
    //  phase G1: Ah 4 slots @0 (16384), Al 4 slots @16384 (16384)
    //  combine:  Y[64][128] f32 @0 (32768)   (A dead)
    //  H:        Hh[64][136] @32768 (17408), Hl @50176 (17408)
    //  phase Z:  Z[64][260] f32 @0 (66560)   (after GEMM2)
    __shared__ __attribute__((aligned(16))) char smem[67584];

    const int tid  = threadIdx.x;
    const int blk  = blockIdx.x;
    const int m0   = blk * CLK;
    const int lane = tid & 63;
    const int wid  = tid >> 6;
    const int ln15 = lane & 15;
    const int q    = lane >> 4;
    const int np1  = wid & 3;    // GEMM1 N-group (cols 32*np1..+31)
    const int gk   = wid >> 2;   // K half: tiles gk*16 .. +15

    // ---- A staging indices: thread = (row 0..63, kq 0..28 step 4)
    const int srow = tid >> 3;
    const int skq  = (tid & 7) * 4;
    const int wby  = srow * 64 + (((skq >> 3) ^ ((srow >> 1) & 3)) << 4) + ((skq >> 2) & 1) * 8;
    const float* aBase = A + (size_t)(m0 + srow) * DM + skq;

    // ---- A frag read byte offsets (within a 4 KB tile slot)
    int aby[4];
    #pragma unroll
    for (int mi = 0; mi < 4; ++mi) {
        int row = 16 * mi + ln15;
        aby[mi] = row * 64 + ((q ^ ((row >> 1) & 3)) << 4);
    }

    const char* wb[2];
    wb[0] = blobs + (32 * np1 + ln15) * 80 + q * 16;
    wb[1] = blobs + (32 * np1 + 16 + ln15) * 80 + q * 16;

    v4f acc1[4][2], acc2[4][2];
    #pragma unroll
    for (int mi = 0; mi < 4; ++mi)
        #pragma unroll
        for (int ni = 0; ni < 2; ++ni) {
            acc1[mi][ni] = (v4f){0.f, 0.f, 0.f, 0.f};
            acc2[mi][ni] = (v4f){0.f, 0.f, 0.f, 0.f};
        }

    // ---- prologue: stage tiles (0,16) direct; fill A ring (tiles 1..4,17..20)
    {
        float4 u0 = *(const float4*)(aBase);
        float4 u1 = *(const float4*)(aBase + 16 * 32);
        cvt_store(u0, smem + wby,        smem + 16384 + wby);
        cvt_store(u1, smem + 4096 + wby, smem + 16384 + 4096 + wby);
    }
    float4 ra[4][2];
    #pragma unroll
    for (int s = 0; s < 4; ++s) {
        ra[s][0] = *(const float4*)(aBase + (size_t)(1 + s) * 32);
        ra[s][1] = *(const float4*)(aBase + (size_t)(17 + s) * 32);
        KEEPF4(ra[s][0]); KEEPF4(ra[s][1]);
    }
    int4 cwh[2], cwl[2];
    #pragma unroll
    for (int ni = 0; ni < 2; ++ni) {
        const char* p = wb[ni] + (size_t)(gk * 16) * W1BLOB_TILE;
        cwh[ni] = *(const int4*)(p);
        cwl[ni] = *(const int4*)(p + 10240);
        KEEPI4(cwh[ni]); KEEPI4(cwl[ni]);
    }
    BAR_LGKM();

    // ---- GEMM1 main loop: 16 steps/wave; per step 24 MFMAs
    for (int jo = 0; jo < 4; ++jo) {
        #pragma unroll
        for (int j2 = 0; j2 < 4; ++j2) {
            const int j = jo * 4 + j2;
            const int p = j2 & 1;                  // parity of step j
            const bool more = (jo < 3) || (j2 < 3);
            if (more) {
                const int sp = p ^ 1;              // parity of step j+1
                cvt_store(ra[j2][0], smem + (sp * 2 + 0) * 4096 + wby,
                                     smem + 16384 + (sp * 2 + 0) * 4096 + wby);
                cvt_store(ra[j2][1], smem + (sp * 2 + 1) * 4096 + wby,
                                     smem + 16384 + (sp * 2 + 1) * 4096 + wby);
                if (j + 5 <= 15) {
                    ra[j2][0] = *(const float4*)(aBase + (size_t)(j + 5) * 32);
                    ra[j2][1] = *(const float4*)(aBase + (size_t)(j + 21) * 32);
                    KEEPF4(ra[j2][0]); KEEPF4(ra[j2][1]);
                }
            }
            int4 nwh[2], nwl[2];
            if (more) {
                #pragma unroll
                for (int ni = 0; ni < 2; ++ni) {
                    const char* pw = wb[ni] + (size_t)(gk * 16 + j + 1) * W1BLOB_TILE;
                    nwh[ni] = *(const int4*)(pw);
                    nwl[ni] = *(const int4*)(pw + 10240);
                    KEEPI4(nwh[ni]); KEEPI4(nwl[ni]);
                }
            }
            const char* ab = smem + (p * 2 + gk) * 4096;
            v8h ah[4], al[4];
            #pragma unroll
            for (int mi = 0; mi < 4; ++mi) {
                ah[mi] = *(const v8h*)(ab + aby[mi]);
                al[mi] = *(const v8h*)(ab + 16384 + aby[mi]);
            }
            U16 h0, h1, l0, l1;
            h0.i = cwh[0]; h1.i = cwh[1]; l0.i = cwl[0]; l1.i = cwl[1];
            #pragma unroll
            for (int mi = 0; mi < 4; ++mi) {
                acc1[mi][0] = MFMA16(ah[mi], h0.h, acc1[mi][0]);
                acc2[mi][0] = MFMA16(ah[mi], l0.h, acc2[mi][0]);
                acc2[mi][0] = MFMA16(al[mi], h0.h, acc2[mi][0]);
                acc1[mi][1] = MFMA16(ah[mi], h1.h, acc1[mi][1]);
                acc2[mi][1] = MFMA16(ah[mi], l1.h, acc2[mi][1]);
                acc2[mi][1] = MFMA16(al[mi], h1.h, acc2[mi][1]);
            }
            if (more) {
                cwh[0] = nwh[0]; cwh[1] = nwh[1];
                cwl[0] = nwl[0]; cwl[1] = nwl[1];
            }
            BAR_LGKM();
        }
    }

    // ---- combine K-split partials; GELU; H split into LDS
    const float inv = 1.f / 4096.f;
    if (gk == 1) {
        #pragma unroll
        for (int mi = 0; mi < 4; ++mi)
            #pragma unroll
            for (int ni = 0; ni < 2; ++ni)
                #pragma unroll
                for (int r = 0; r < 4; ++r) {
                    int row = 16 * mi + 4 * q + r;
                    int col = 32 * np1 + 16 * ni + ln15;
                    *(float*)(smem + row * 512 + col * 4) =
                        acc1[mi][ni][r] + acc2[mi][ni][r] * inv;
                }
    }
    BAR_LGKM();
    if (gk == 0) {
        #pragma unroll
        for (int mi = 0; mi < 4; ++mi)
            #pragma unroll
            for (int ni = 0; ni < 2; ++ni) {
                int col = 32 * np1 + 16 * ni + ln15;
                float bv = b1[col];
                #pragma unroll
                for (int r = 0; r < 4; ++r) {
                    int row = 16 * mi + 4 * q + r;
                    float y = acc1[mi][ni][r] + acc2[mi][ni][r] * inv
                            + *(const float*)(smem + row * 512 + col * 4) + bv;
                    float h = 0.5f * y * (1.f + erff(y * 0.70710678118654752f));
                    _Float16 hh = (_Float16)h;
                    _Float16 hl = (_Float16)((h - (float)hh) * 4096.f);
                    int byte_ = row * 272 + ((((col >> 3) ^ ((row >> 1) & 3))) << 4)
                              + (col & 7) * 2;
                    *(_Float16*)(smem + 32768 + byte_) = hh;
                    *(_Float16*)(smem + 50176 + byte_) = hl;
                }
            }
    }
    BAR_LGKM();

    // ---- GEMM2: out 64x256; wave wid covers cols 32*wid..+31; K=128
    v4f c1[4][2], c2[4][2];
    #pragma unroll
    for (int mi = 0; mi < 4; ++mi)
        #pragma unroll
        for (int ni = 0; ni < 2; ++ni) {
            c1[mi][ni] = (v4f){0.f, 0.f, 0.f, 0.f};
            c2[mi][ni] = (v4f){0.f, 0.f, 0.f, 0.f};
        }
    const char* w2b[2];
    w2b[0] = blobs + W2BLOB_BASE + (32 * wid + ln15) * 80 + q * 16;
    w2b[1] = blobs + W2BLOB_BASE + (32 * wid + 16 + ln15) * 80 + q * 16;

    #pragma unroll
    for (int ks = 0; ks < 4; ++ks) {
        v8h hh[4], hl[4];
        #pragma unroll
        for (int mi = 0; mi < 4; ++mi) {
            int frow = 16 * mi + ln15;
            int byte_ = frow * 272 + ((4 * ks + (q ^ ((frow >> 1) & 3))) << 4);
            hh[mi] = *(const v8h*)(smem + 32768 + byte_);
            hl[mi] = *(const v8h*)(smem + 50176 + byte_);
        }
        #pragma unroll
        for (int ni = 0; ni < 2; ++ni) {
            U16 wh_, wl_;
            wh_.i = *(const int4*)(w2b[ni] + (size_t)ks * W2BLOB_TILE);
            wl_.i = *(const int4*)(w2b[ni] + (size_t)ks * W2BLOB_TILE + 20480);
            #pragma unroll
            for (int mi = 0; mi < 4; ++mi) {
                c1[mi][ni] = MFMA16(hh[mi], wh_.h, c1[mi][ni]);
                c2[mi][ni] = MFMA16(hh[mi], wl_.h, c2[mi][ni]);
                c2[mi][ni] = MFMA16(hl[mi], wh_.h, c2[mi][ni]);
            }
        }
    }
    BAR_LGKM();   // H dead; Z region free

    // ---- z = pi*tanh(y2) -> Z LDS
    #pragma unroll
    for (int mi = 0; mi < 4; ++mi)
        #pragma unroll
        for (int ni = 0; ni < 2; ++ni) {
            int col = 32 * wid + 16 * ni + ln15;
            float bv = b2[col];
            #pragma unroll
            for (int r = 0; r < 4; ++r) {
                int row = 16 * mi + 4 * q + r;
                float y2 = c1[mi][ni][r] + c2[mi][ni][r] * inv + bv;
                *(float*)(smem + row * 1040 + col * 4) =
                    3.14159265358979323846f * tanhf(y2);
            }
        }
    BAR_LGKM();

    // ---- scan (waves 0-3) + fills (waves 4-7)
    if (tid < 256) {
        const int c = tid;
        const float Pi = expf(logPi[c]);
        const float Rr = expf(logR[c]);
        const float Kc = Pi / fmaxf(Pi + Rr, 1e-8f);
        const float alpha = 1.f - Kc;
        float d = 0.f;
        float tv[2][16];
        #pragma unroll
        for (int i = 0; i < 16; ++i)
            tv[0][i] = theta[(size_t)(m0 + i) * HNB + c];
        #pragma unroll
        for (int g = 0; g < 4; ++g) {
            const int cur = g & 1;
            if (g < 3) {
                #pragma unroll
                for (int i = 0; i < 16; ++i)
                    tv[cur ^ 1][i] = theta[(size_t)(m0 + (g + 1) * 16 + i) * HNB + c];
            }
            float sv[16];
            #pragma unroll
            for (int i = 0; i < 16; ++i) {
                float z = *(const float*)(smem + (g * 16 + i) * 1040 + c * 4);
                float diff = z - tv[cur][i];
                float kq = rintf(diff * 0.15915494309189533577f);
                float nu = (float)((double)diff - (double)kq * 6.283185307179586476925286766559);
                d = fmaf(alpha, d, Kc * nu);
                sv[i] = tv[cur][i] + d;
            }
            #pragma unroll
            for (int i = 0; i < 16; ++i)
                out0[(size_t)(m0 + g * 16 + i) * HNB + c] = sv[i];
        }
        carry[(size_t)blk * cstride + c] = d;
    } else {
        const int c = tid - 256;
        const float Pi = expf(logPi[c]);
        const float Rr = expf(logR[c]);
        const float Kc = Pi / fmaxf(Pi + Rr, 1e-8f);
        if (fill1) {
            #pragma unroll 4
            for (int i = 0; i < CLK; ++i) {
                size_t idx = (size_t)(m0 + i) * HNB + c;
                out2[idx]  = Kc;
                fill1[idx] = Pi;
                fill3[idx] = Rr;
            }
        } else {
            #pragma unroll 4
            for (int i = 0; i < CLK; ++i)
                out2[(size_t)(m0 + i) * HNB + c] = Kc;
        }
    }
}

// ---------------------------------------------------------------------------
// K2: exclusive scan of chunk carries (factor alpha^64), one block per batch.
//     Writes incoming D to slot +c and replicated +crep+c (for apply halves).
// ---------------------------------------------------------------------------
__global__ __launch_bounds__(256) void k_cscan(
    const float* __restrict__ logPi, const float* __restrict__ logR,
    float* carry, int cstride, int crep)
{
    const int c = threadIdx.x, b = blockIdx.x;
    const float Pi = expf(logPi[c]);
    const float Rr = expf(logR[c]);
    const float alpha = 1.f - Pi / fmaxf(Pi + Rr, 1e-8f);
    float A64 = alpha;
    #pragma unroll
    for (int i = 0; i < 6; ++i) A64 *= A64;
    float D = 0.f;
    for (int s0 = 0; s0 < CPB; s0 += 16) {
        float a[16];
        #pragma unroll
        for (int j = 0; j < 16; ++j)
            a[j] = carry[(size_t)(b * CPB + s0 + j) * cstride + c];
        #pragma unroll
        for (int j = 0; j < 16; ++j) {
            size_t base = (size_t)(b * CPB + s0 + j) * cstride;
            carry[base + c]        = D;
            carry[base + crep + c] = D;
            D = fmaf(A64, D, a[j]);
        }
    }
}

// ---------------------------------------------------------------------------
// K3: out0 += alpha^(i+1)*D; in fallback mode also fills Pi/R.
//     grid 512 = (chunk, 32-row half); D read-before-fill from own slot.
// ---------------------------------------------------------------------------
__global__ __launch_bounds__(256) void k_apply(
    const float* __restrict__ logPi, const float* __restrict__ logR,
    float* __restrict__ out0, float* out1, float* out3,
    const float* carry, int cstride, int crep, int do_fills)
{
    const int blk = blockIdx.x;
    const int chunk = blk >> 1, half = blk & 1;
    const int c = threadIdx.x;
    const float Pi = expf(logPi[c]);
    const float Rr = expf(logR[c]);
    const float Kc = Pi / fmaxf(Pi + Rr, 1e-8f);
    const float alpha = 1.f - Kc;
    float D = carry[(size_t)chunk * cstride + (size_t)half * crep + c];
    float w = alpha * D;
    if (half) {
        float a32 = alpha;
        #pragma unroll
        for (int i = 0; i < 5; ++i) a32 *= a32;   // alpha^32
        w *= a32;
    }
    const size_t base = (size_t)chunk * (CLK * HNB) + (size_t)half * (32 * HNB) + c;
    if (do_fills) {
        #pragma unroll 4
        for (int i = 0; i < 32; ++i) {
            size_t idx = base + (size_t)i * HNB;
            out0[idx] += w;
            out1[idx] = Pi;
            out3[idx] = Rr;
            w *= alpha;
        }
    } else {
        #pragma unroll 4
        for (int i = 0; i < 32; ++i) {
            size_t idx = base + (size_t)i * HNB;
            out0[idx] += w;
            w *= alpha;
        }
    }
}

extern "C" void kernel_launch(void* const* d_in, const int* in_sizes, int n_in,
                              void* d_out, int out_size, void* d_ws, size_t ws_size,
                              hipStream_t stream) {
    const float* theta   = (const float*)d_in[0];
    const float* content = (const float*)d_in[1];
    const float* W1      = (const float*)d_in[2];
    const float* b1      = (const float*)d_in[3];
    const float* W2      = (const float*)d_in[4];
    const float* b2      = (const float*)d_in[5];
    const float* logPi   = (const float*)d_in[6];
    const float* logR    = (const float*)d_in[7];

    float* out  = (float*)d_out;
    float* out0 = out;
    float* out1 = out + (size_t)MTOT * HNB;
    float* out2 = out + (size_t)2 * MTOT * HNB;
    float* out3 = out + (size_t)3 * MTOT * HNB;

    const size_t carry_bytes = (size_t)NBLK * 512 * 4;          // 512 KB
    const size_t need = carry_bytes + BLOB_BYTES;               // ~1.34 MB
    float* carry; int cstride, crep, do_fills; char* blobs;
    float *f1, *f3;
    if (ws_size >= need) {
        carry   = (float*)d_ws;
        cstride = 512; crep = 256;
        blobs   = (char*)d_ws + carry_bytes;
        f1 = out1; f3 = out3; do_fills = 0;
    } else {
        carry   = out3;                 // per-chunk slots inside out3
        cstride = 16384; crep = 8192;
        blobs   = (char*)out1;          // blobs live in out1 until k_apply fills
        f1 = nullptr; f3 = nullptr; do_fills = 1;
    }

    hipLaunchKernelGGL(k_prep, dim3(36), dim3(256), 0, stream, W1, W2, blobs);
    hipLaunchKernelGGL(k_mega, dim3(NBLK), dim3(512), 0, stream,
                       content, theta, b1, b2, logPi, logR, blobs,
                       out0, out2, f1, f3, carry, cstride);
    hipLaunchKernelGGL(k_cscan, dim3(NBAT), dim3(256), 0, stream,
                       logPi, logR, carry, cstride, crep);
    hipLaunchKernelGGL(k_apply, dim3(NBLK * 2), dim3(256), 0, stream,
                       logPi, logR, out0, out1, out3, carry, cstride, crep, do_fills);
}

// Round 9
// 59.346 us; speedup vs baseline: 1.1994x; 1.1994x over previous
//
#include <hip/hip_runtime.h>
#include <math.h>

// Problem geometry
#define MTOT  16384      // B*L
#define DM    1024
#define HIDN  128
#define HNB   256
#define NBAT  4
#define CLK   64         // rows per k_mega block == scan chunk
#define NBLK  256        // MTOT/CLK
#define CPB   64         // chunks per batch (4096/64)

typedef _Float16 v8h __attribute__((ext_vector_type(8)));
typedef float    v4f __attribute__((ext_vector_type(4)));
typedef int      v4i __attribute__((ext_vector_type(4)));
#define MFMA16(a,b,c) __builtin_amdgcn_mfma_f32_16x16x32_f16((a),(b),(c),0,0,0)

// Weight blobs (d_ws when big enough, else out1 region):
//  [0,655360):      W1 k-tiles kt=0..31, 20480 B: {W1h[col=128][40 fp16] | W1l}
//  [655360,819200): W2 k-tiles ks=0..3, 40960 B: {W2h[col=256][40] | W2l}
#define W1BLOB_TILE 20480
#define W2BLOB_BASE 655360
#define W2BLOB_TILE 40960
#define BLOB_BYTES  819200

// k_mega LDS map (149504 B total):
//  G1 phase : raw A fp32 [2 slot][2 gk][64 rows][128B]  @0      (32768)
//             split Ah   [2 gk][2 buf][64][32] fp16     @32768  (16384)
//             split Al                                  @49152  (16384)
//             W1 dbuf    [2 buf][gk0|gk1 20480]         @65536  (81920) ..147456
//  combine  : Y lane-linear scratch                     @0      (32768)  (raw dead)
//  H        : Hh [64][272B] @32768 (17408) | Hl @50176  (..67584)        (split dead)
//  GEMM2    : W2 dbuf [2 buf][40960]                    @67584  (..149504) (W1 dead)
//  Z        : [64][260] f32                             @0      (66560)  (Y/H dead)
#define RAW0   0
#define AH0    32768
#define AL0    49152
#define W1L    65536
#define YOFF   0
#define HH0    32768
#define HL0    50176
#define W2L    67584
#define ZOFF   0
#define SMEMSZ 149504

#define VMCNT(N) asm volatile("s_waitcnt vmcnt(" #N ")" ::: "memory")
#define BARRIER() do { asm volatile("s_waitcnt lgkmcnt(0)" ::: "memory"); \
                       __builtin_amdgcn_s_barrier(); } while (0)

typedef const __attribute__((address_space(1))) void* gas1_t;
typedef __attribute__((address_space(3))) void* las3_t;

__device__ __forceinline__ void gld16(const void* g, void* l) {
    __builtin_amdgcn_global_load_lds((gas1_t)g, (las3_t)l, 16, 0, 0);
}

__device__ __forceinline__ void split8(v4f a, v4f b, v4i* H, v4i* L) {
    union { _Float16 h[8]; v4i v; } hh, ll;
    #pragma unroll
    for (int e = 0; e < 4; ++e) {
        _Float16 t0 = (_Float16)a[e];
        hh.h[e] = t0;
        ll.h[e] = (_Float16)((a[e] - (float)t0) * 4096.f);
        _Float16 t1 = (_Float16)b[e];
        hh.h[e + 4] = t1;
        ll.h[e + 4] = (_Float16)((b[e] - (float)t1) * 4096.f);
    }
    *H = hh.v; *L = ll.v;
}

// ---------------------------------------------------------------------------
// K0: convert+transpose+pad weights into fp16 split blobs (unchanged R4-R8).
// ---------------------------------------------------------------------------
__global__ __launch_bounds__(256) void k_prep(
    const float* __restrict__ W1,   // [1024][128]
    const float* __restrict__ W2,   // [128][256]
    char* __restrict__ blobs)
{
    __shared__ float lds[32][260];
    const int t = threadIdx.x, blk = blockIdx.x;
    if (blk < 32) {
        const int k0 = blk * 32;
        #pragma unroll
        for (int i = 0; i < 4; ++i) {
            int j = t + i * 256;
            int k = j >> 5, n4 = (j & 31) << 2;
            *(float4*)&lds[k][n4] = *(const float4*)&W1[(size_t)(k0 + k) * HIDN + n4];
        }
        __syncthreads();
        const int n = t >> 1, kh = t & 1;
        union { _Float16 h[16]; int2 v[4]; } uh, ul;
        #pragma unroll
        for (int kk = 0; kk < 16; ++kk) {
            float v = lds[kh * 16 + kk][n];
            _Float16 hh = (_Float16)v;
            uh.h[kk] = hh;
            ul.h[kk] = (_Float16)((v - (float)hh) * 4096.f);
        }
        char* bh = blobs + blk * W1BLOB_TILE + n * 80 + kh * 32;
        #pragma unroll
        for (int i = 0; i < 4; ++i) {
            *(int2*)(bh + i * 8)         = uh.v[i];
            *(int2*)(bh + 10240 + i * 8) = ul.v[i];
        }
        if (kh == 1) {
            int2 z; z.x = 0; z.y = 0;
            char* ph = blobs + blk * W1BLOB_TILE + n * 80 + 64;
            *(int2*)(ph) = z; *(int2*)(ph + 8) = z;
            *(int2*)(ph + 10240) = z; *(int2*)(ph + 10240 + 8) = z;
        }
    } else {
        const int ks = blk - 32, k0 = ks * 32;
        #pragma unroll
        for (int i = 0; i < 8; ++i) {
            int j = t + i * 256;
            int k = j >> 6, n4 = (j & 63) << 2;
            *(float4*)&lds[k][n4] = *(const float4*)&W2[(size_t)(k0 + k) * HNB + n4];
        }
        __syncthreads();
        const int n = t;
        union { _Float16 h[40]; int2 v[10]; } uh, ul;
        #pragma unroll
        for (int kk = 0; kk < 32; ++kk) {
            float v = lds[kk][n];
            _Float16 hh = (_Float16)v;
            uh.h[kk] = hh;
            ul.h[kk] = (_Float16)((v - (float)hh) * 4096.f);
        }
        #pragma unroll
        for (int kk = 32; kk < 40; ++kk) { uh.h[kk] = (_Float16)0.f; ul.h[kk] = (_Float16)0.f; }
        char* bh = blobs + W2BLOB_BASE + ks * W2BLOB_TILE + n * 80;
        #pragma unroll
        for (int i = 0; i < 10; ++i) {
            *(int2*)(bh + i * 8)         = uh.v[i];
            *(int2*)(bh + 20480 + i * 8) = ul.v[i];
        }
    }
}

// ---------------------------------------------------------------------------
// K1: mega. Block = 64 rows = one chunk; 512 thr (8 waves = 4 np x 2 gk),
// grid 256. GEMM1 wave tile 64x32 (mP=4,nP=2), in-block K-split, combine.
// All global->LDS via global_load_lds with counted vmcnt (issue pinned):
//   A: glds raw fp32 2-slot ring (dist-2, bank-deswizzled source) ->
//      per-wave cvt (wave converts the rows it staged) -> split fp16 dbuf.
//   W1/W2: glds byte-copy of the blob tile into LDS dbuf (dist-1).
// Barriers drain lgkm only; vmcnt ledger: per step issue [W x5, A x2];
// waits vmcnt(7) (raw ready) then vmcnt(2) (W ready, A stays in flight).
// ---------------------------------------------------------------------------
__global__ __launch_bounds__(512, 2) void k_mega(
    const float* __restrict__ A,      // content [16384][1024]
    const float* __restrict__ theta,  // [16384][256]
    const float* __restrict__ b1, const float* __restrict__ b2,
    const float* __restrict__ logPi, const float* __restrict__ logR,
    const char* __restrict__ blobs,
    float* __restrict__ out0, float* __restrict__ out2,
    float* fill1, float* fill3,       // non-null only in ws mode
    float* carry, int cstride)
{
    __shared__ __attribute__((aligned(16))) char smem[SMEMSZ];

    const int tid  = threadIdx.x;
    const int blk  = blockIdx.x;
    const int m0   = blk * CLK;
    const int lane = tid & 63;
    const int wid  = tid >> 6;
    const int ln15 = lane & 15;
    const int q    = lane >> 4;
    const int np1  = wid & 3;    // GEMM1 N-group (cols 32*np1..+31)
    const int gk   = wid >> 2;   // K half

    // ---- A raw staging (per wave: 2 glds/step, rows (wid&3)*16..+15 of half wid>>2)
    const int rowoff0 = (wid & 3) * 16 + (lane >> 3);
    const int rowoff1 = rowoff0 + 8;
    const int swf = ((lane & 7) ^ (lane >> 3)) * 4;       // pre-swizzled source (floats)
    const float* aSrc0 = A + (size_t)(m0 + rowoff0) * DM + (size_t)(wid >> 2) * 512 + swf;
    const float* aSrc1 = A + (size_t)(m0 + rowoff1) * DM + (size_t)(wid >> 2) * 512 + swf;
    const int rawDst = (wid >> 2) * 8192 + (wid & 3) * 2048;   // + i*1024 + slot*16384

    // ---- cvt indices (wave converts its own staged rows)
    const int crow = (wid & 3) * 16 + (lane >> 2);
    const int cseg = lane & 3;
    const int cvtRowOff = (wid >> 2) * 8192 + crow * 128;
    const int rb0 = ((2 * cseg)     ^ (crow & 7)) * 16;
    const int rb1 = ((2 * cseg + 1) ^ (crow & 7)) * 16;
    const int wbyC = crow * 64 + ((cseg ^ ((crow >> 1) & 3)) << 4);
    const int sh = wid >> 2;

    // ---- W1 staging source (wave slice of 40960B concat tile-pair)
    const char* wSrc = blobs + (size_t)(wid >> 2) * 16 * W1BLOB_TILE
                     + (size_t)(wid & 3) * 5120 + (size_t)lane * 16;

    // ---- A frag read byte offsets
    int aby[4];
    #pragma unroll
    for (int mi = 0; mi < 4; ++mi) {
        int row = 16 * mi + ln15;
        aby[mi] = row * 64 + ((q ^ ((row >> 1) & 3)) << 4);
    }

    v4f acc1[4][2], acc2[4][2];
    #pragma unroll
    for (int mi = 0; mi < 4; ++mi)
        #pragma unroll
        for (int ni = 0; ni < 2; ++ni) {
            acc1[mi][ni] = (v4f){0.f, 0.f, 0.f, 0.f};
            acc2[mi][ni] = (v4f){0.f, 0.f, 0.f, 0.f};
        }

    // ---- prologue: raw(0)->slot0, W(0)->buf0, raw(1)->slot1
    gld16(aSrc0, smem + RAW0 + rawDst);
    gld16(aSrc1, smem + RAW0 + rawDst + 1024);
    #pragma unroll
    for (int i = 0; i < 5; ++i)
        gld16(wSrc + i * 1024, smem + W1L + wid * 5120 + i * 1024);
    gld16(aSrc0 + 32, smem + RAW0 + 16384 + rawDst);
    gld16(aSrc1 + 32, smem + RAW0 + 16384 + rawDst + 1024);
    VMCNT(7);                       // raw(0) landed
    {
        const char* rb = smem + RAW0 + cvtRowOff;
        v4f r0 = *(const v4f*)(rb + rb0);
        v4f r1 = *(const v4f*)(rb + rb1);
        v4i Hq, Lq; split8(r0, r1, &Hq, &Lq);
        *(v4i*)(smem + AH0 + sh * 8192 + wbyC) = Hq;
        *(v4i*)(smem + AL0 + sh * 8192 + wbyC) = Lq;
    }
    VMCNT(2);                       // W(0) landed; raw(1) in flight
    BARRIER();

    // ---- GEMM1 main loop: 16 k-steps
    #pragma unroll
    for (int kt = 0; kt < 16; ++kt) {
        const int buf = kt & 1, nb = buf ^ 1;
        if (kt < 15) {              // issue W(kt+1) -> buf nb
            const char* ws = wSrc + (size_t)(kt + 1) * W1BLOB_TILE;
            char* wd = smem + W1L + nb * 40960 + wid * 5120;
            #pragma unroll
            for (int i = 0; i < 5; ++i) gld16(ws + i * 1024, wd + i * 1024);
        }
        if (kt < 14) {              // issue raw(kt+2) -> slot kt&1
            char* rd = smem + RAW0 + buf * 16384 + rawDst;
            gld16(aSrc0 + (size_t)(kt + 2) * 32, rd);
            gld16(aSrc1 + (size_t)(kt + 2) * 32, rd + 1024);
        }
        // compute step kt
        {
            const char* abH = smem + AH0 + gk * 8192 + buf * 4096;
            const char* abL = smem + AL0 + gk * 8192 + buf * 4096;
            const char* wb  = smem + W1L + buf * 40960 + gk * 20480;
            v8h ah[4], al[4];
            #pragma unroll
            for (int mi = 0; mi < 4; ++mi) {
                ah[mi] = *(const v8h*)(abH + aby[mi]);
                al[mi] = *(const v8h*)(abL + aby[mi]);
            }
            #pragma unroll
            for (int ni = 0; ni < 2; ++ni) {
                const int wo = (32 * np1 + 16 * ni + ln15) * 80 + q * 16;
                v8h wfh = *(const v8h*)(wb + wo);
                v8h wfl = *(const v8h*)(wb + 10240 + wo);
                #pragma unroll
                for (int mi = 0; mi < 4; ++mi) {
                    acc1[mi][ni] = MFMA16(ah[mi], wfh, acc1[mi][ni]);
                    acc2[mi][ni] = MFMA16(ah[mi], wfl, acc2[mi][ni]);
                    acc2[mi][ni] = MFMA16(al[mi], wfh, acc2[mi][ni]);
                }
            }
        }
        // cvt raw(kt+1) (slot nb) -> split buf nb
        if (kt < 15) {
            if (kt < 14) { VMCNT(7); } else { VMCNT(5); }
            const char* rb = smem + RAW0 + nb * 16384 + cvtRowOff;
            v4f r0 = *(const v4f*)(rb + rb0);
            v4f r1 = *(const v4f*)(rb + rb1);
            v4i Hq, Lq; split8(r0, r1, &Hq, &Lq);
            *(v4i*)(smem + AH0 + sh * 8192 + nb * 4096 + wbyC) = Hq;
            *(v4i*)(smem + AL0 + sh * 8192 + nb * 4096 + wbyC) = Lq;
        }
        if (kt < 14) { VMCNT(2); }          // W(kt+1) done; raw(kt+2) in flight
        else if (kt == 14) { VMCNT(0); }    // everything drained
        BARRIER();
    }

    // ---- issue W2(0) glds (arrives during combine+GELU)
    const char* w2Src = blobs + W2BLOB_BASE + (size_t)wid * 5120 + (size_t)lane * 16;
    #pragma unroll
    for (int i = 0; i < 5; ++i)
        gld16(w2Src + i * 1024, smem + W2L + wid * 5120 + i * 1024);

    const float inv = 1.f / 4096.f;
    // ---- combine: gk1 writes lane-linear partials
    if (gk == 1) {
        #pragma unroll
        for (int mi = 0; mi < 4; ++mi)
            #pragma unroll
            for (int ni = 0; ni < 2; ++ni) {
                v4f y = acc1[mi][ni] + acc2[mi][ni] * inv;
                *(v4f*)(smem + YOFF + np1 * 8192 + (mi * 2 + ni) * 1024 + lane * 16) = y;
            }
    }
    BARRIER();
    // ---- GELU: gk0 combines + writes H split (swizzled)
    if (gk == 0) {
        #pragma unroll
        for (int mi = 0; mi < 4; ++mi)
            #pragma unroll
            for (int ni = 0; ni < 2; ++ni) {
                v4f yo = *(const v4f*)(smem + YOFF + np1 * 8192 + (mi * 2 + ni) * 1024 + lane * 16);
                const int col = 32 * np1 + 16 * ni + ln15;
                const float bv = b1[col];
                #pragma unroll
                for (int r = 0; r < 4; ++r) {
                    float y = acc1[mi][ni][r] + acc2[mi][ni][r] * inv + yo[r] + bv;
                    float h = 0.5f * y * (1.f + erff(y * 0.70710678118654752f));
                    _Float16 hh2 = (_Float16)h;
                    _Float16 hl2 = (_Float16)((h - (float)hh2) * 4096.f);
                    const int row = 16 * mi + 4 * q + r;
                    const int byte_ = row * 272 + ((((col >> 3) ^ ((row >> 1) & 3))) << 4)
                                    + (col & 7) * 2;
                    *(_Float16*)(smem + HH0 + byte_) = hh2;
                    *(_Float16*)(smem + HL0 + byte_) = hl2;
                }
            }
    }
    BARRIER();
    VMCNT(0);       // W2(0) staged (per-wave) ...
    BARRIER();      // ... and cross-wave

    // ---- GEMM2: out 64x256; wave wid = cols 32*wid..+31 (nP=2, mP=4); K=128
    v4f c1[4][2], c2[4][2];
    #pragma unroll
    for (int mi = 0; mi < 4; ++mi)
        #pragma unroll
        for (int ni = 0; ni < 2; ++ni) {
            c1[mi][ni] = (v4f){0.f, 0.f, 0.f, 0.f};
            c2[mi][ni] = (v4f){0.f, 0.f, 0.f, 0.f};
        }
    #pragma unroll
    for (int ks = 0; ks < 4; ++ks) {
        if (ks < 3) {               // issue W2(ks+1) -> buf (ks+1)&1
            const char* ws = w2Src + (size_t)(ks + 1) * W2BLOB_TILE;
            char* wd = smem + W2L + ((ks + 1) & 1) * 40960 + wid * 5120;
            #pragma unroll
            for (int i = 0; i < 5; ++i) gld16(ws + i * 1024, wd + i * 1024);
        }
        const char* w2b = smem + W2L + (ks & 1) * 40960;
        v8h hh[4], hl[4];
        #pragma unroll
        for (int mi = 0; mi < 4; ++mi) {
            int frow = 16 * mi + ln15;
            int hby = frow * 272 + ((4 * ks + (q ^ ((frow >> 1) & 3))) << 4);
            hh[mi] = *(const v8h*)(smem + HH0 + hby);
            hl[mi] = *(const v8h*)(smem + HL0 + hby);
        }
        #pragma unroll
        for (int ni = 0; ni < 2; ++ni) {
            const int wo2 = (32 * wid + 16 * ni + ln15) * 80 + q * 16;
            v8h w2h = *(const v8h*)(w2b + wo2);
            v8h w2l = *(const v8h*)(w2b + 20480 + wo2);
            #pragma unroll
            for (int mi = 0; mi < 4; ++mi) {
                c1[mi][ni] = MFMA16(hh[mi], w2h, c1[mi][ni]);
                c2[mi][ni] = MFMA16(hh[mi], w2l, c2[mi][ni]);
                c2[mi][ni] = MFMA16(hl[mi], w2h, c2[mi][ni]);
            }
        }
        VMCNT(0);
        BARRIER();
    }

    // ---- z = pi*tanh(y2) -> Z LDS
    #pragma unroll
    for (int mi = 0; mi < 4; ++mi)
        #pragma unroll
        for (int ni = 0; ni < 2; ++ni) {
            int col = 32 * wid + 16 * ni + ln15;
            float bv = b2[col];
            #pragma unroll
            for (int r = 0; r < 4; ++r) {
                int row = 16 * mi + 4 * q + r;
                float y2 = c1[mi][ni][r] + c2[mi][ni][r] * inv + bv;
                *(float*)(smem + ZOFF + row * 1040 + col * 4) =
                    3.14159265358979323846f * tanhf(y2);
            }
        }
    BARRIER();

    // ---- scan (waves 0-3) + fills (waves 4-7)
    if (tid < 256) {
        const int c = tid;
        const float Pi = expf(logPi[c]);
        const float Rr = expf(logR[c]);
        const float Kc = Pi / fmaxf(Pi + Rr, 1e-8f);
        const float alpha = 1.f - Kc;
        float d = 0.f;
        float tv[2][16];
        #pragma unroll
        for (int i = 0; i < 16; ++i)
            tv[0][i] = theta[(size_t)(m0 + i) * HNB + c];
        #pragma unroll
        for (int g = 0; g < 4; ++g) {
            const int cur = g & 1;
            if (g < 3) {
                #pragma unroll
                for (int i = 0; i < 16; ++i)
                    tv[cur ^ 1][i] = theta[(size_t)(m0 + (g + 1) * 16 + i) * HNB + c];
            }
            float sv[16];
            #pragma unroll
            for (int i = 0; i < 16; ++i) {
                float z = *(const float*)(smem + ZOFF + (g * 16 + i) * 1040 + c * 4);
                float diff = z - tv[cur][i];
                float kq = rintf(diff * 0.15915494309189533577f);
                float nu = (float)((double)diff - (double)kq * 6.283185307179586476925286766559);
                d = fmaf(alpha, d, Kc * nu);
                sv[i] = tv[cur][i] + d;
            }
            #pragma unroll
            for (int i = 0; i < 16; ++i)
                out0[(size_t)(m0 + g * 16 + i) * HNB + c] = sv[i];
        }
        carry[(size_t)blk * cstride + c] = d;
    } else {
        const int c = tid - 256;
        const float Pi = expf(logPi[c]);
        const float Rr = expf(logR[c]);
        const float Kc = Pi / fmaxf(Pi + Rr, 1e-8f);
        if (fill1) {
            #pragma unroll 4
            for (int i = 0; i < CLK; ++i) {
                size_t idx = (size_t)(m0 + i) * HNB + c;
                out2[idx]  = Kc;
                fill1[idx] = Pi;
                fill3[idx] = Rr;
            }
        } else {
            #pragma unroll 4
            for (int i = 0; i < CLK; ++i)
                out2[(size_t)(m0 + i) * HNB + c] = Kc;
        }
    }
}

// ---------------------------------------------------------------------------
// K2: exclusive scan of chunk carries (factor alpha^64), one block per batch.
// ---------------------------------------------------------------------------
__global__ __launch_bounds__(256) void k_cscan(
    const float* __restrict__ logPi, const float* __restrict__ logR,
    float* carry, int cstride, int crep)
{
    const int c = threadIdx.x, b = blockIdx.x;
    const float Pi = expf(logPi[c]);
    const float Rr = expf(logR[c]);
    const float alpha = 1.f - Pi / fmaxf(Pi + Rr, 1e-8f);
    float A64 = alpha;
    #pragma unroll
    for (int i = 0; i < 6; ++i) A64 *= A64;
    float D = 0.f;
    for (int s0 = 0; s0 < CPB; s0 += 16) {
        float a[16];
        #pragma unroll
        for (int j = 0; j < 16; ++j)
            a[j] = carry[(size_t)(b * CPB + s0 + j) * cstride + c];
        #pragma unroll
        for (int j = 0; j < 16; ++j) {
            size_t base = (size_t)(b * CPB + s0 + j) * cstride;
            carry[base + c]        = D;
            carry[base + crep + c] = D;
            D = fmaf(A64, D, a[j]);
        }
    }
}

// ---------------------------------------------------------------------------
// K3: out0 += alpha^(i+1)*D; in fallback mode also fills Pi/R.
//     grid 512 = (chunk, 32-row half).
// ---------------------------------------------------------------------------
__global__ __launch_bounds__(256) void k_apply(
    const float* __restrict__ logPi, const float* __restrict__ logR,
    float* __restrict__ out0, float* out1, float* out3,
    const float* carry, int cstride, int crep, int do_fills)
{
    const int blk = blockIdx.x;
    const int chunk = blk >> 1, half = blk & 1;
    const int c = threadIdx.x;
    const float Pi = expf(logPi[c]);
    const float Rr = expf(logR[c]);
    const float Kc = Pi / fmaxf(Pi + Rr, 1e-8f);
    const float alpha = 1.f - Kc;
    float D = carry[(size_t)chunk * cstride + (size_t)half * crep + c];
    float w = alpha * D;
    if (half) {
        float a32 = alpha;
        #pragma unroll
        for (int i = 0; i < 5; ++i) a32 *= a32;   // alpha^32
        w *= a32;
    }
    const size_t base = (size_t)chunk * (CLK * HNB) + (size_t)half * (32 * HNB) + c;
    if (do_fills) {
        #pragma unroll 4
        for (int i = 0; i < 32; ++i) {
            size_t idx = base + (size_t)i * HNB;
            out0[idx] += w;
            out1[idx] = Pi;
            out3[idx] = Rr;
            w *= alpha;
        }
    } else {
        #pragma unroll 4
        for (int i = 0; i < 32; ++i) {
            size_t idx = base + (size_t)i * HNB;
            out0[idx] += w;
            w *= alpha;
        }
    }
}

extern "C" void kernel_launch(void* const* d_in, const int* in_sizes, int n_in,
                              void* d_out, int out_size, void* d_ws, size_t ws_size,
                              hipStream_t stream) {
    const float* theta   = (const float*)d_in[0];
    const float* content = (const float*)d_in[1];
    const float* W1      = (const float*)d_in[2];
    const float* b1      = (const float*)d_in[3];
    const float* W2      = (const float*)d_in[4];
    const float* b2      = (const float*)d_in[5];
    const float* logPi   = (const float*)d_in[6];
    const float* logR    = (const float*)d_in[7];

    float* out  = (float*)d_out;
    float* out0 = out;
    float* out1 = out + (size_t)MTOT * HNB;
    float* out2 = out + (size_t)2 * MTOT * HNB;
    float* out3 = out + (size_t)3 * MTOT * HNB;

    const size_t carry_bytes = (size_t)NBLK * 512 * 4;          // 512 KB
    const size_t need = carry_bytes + BLOB_BYTES;               // ~1.34 MB
    float* carry; int cstride, crep, do_fills; char* blobs;
    float *f1, *f3;
    if (ws_size >= need) {
        carry   = (float*)d_ws;
        cstride = 512; crep = 256;
        blobs   = (char*)d_ws + carry_bytes;
        f1 = out1; f3 = out3; do_fills = 0;
    } else {
        carry   = out3;
        cstride = 16384; crep = 8192;
        blobs   = (char*)out1;
        f1 = nullptr; f3 = nullptr; do_fills = 1;
    }

    hipLaunchKernelGGL(k_prep, dim3(36), dim3(256), 0, stream, W1, W2, blobs);
    hipLaunchKernelGGL(k_mega, dim3(NBLK), dim3(512), 0, stream,
                       content, theta, b1, b2, logPi, logR, blobs,
                       out0, out2, f1, f3, carry, cstride);
    hipLaunchKernelGGL(k_cscan, dim3(NBAT), dim3(256), 0, stream,
                       logPi, logR, carry, cstride, crep);
    hipLaunchKernelGGL(k_apply, dim3(NBLK * 2), dim3(256), 0, stream,
                       logPi, logR, out0, out1, out3, carry, cstride, crep, do_fills);
}